// Round 8
// baseline (179.020 us; speedup 1.0000x reference)
//
#include <hip/hip_runtime.h>

// Problem constants (from reference setup_inputs)
constexpr int B  = 32;
constexpr int H  = 256;
constexpr int W  = 1216;
constexpr int HW = H * W;            // 311296 (divisible by 4)
constexpr int N  = B * HW;           // 9961472 elements in gt / weight_map
constexpr int NCHUNK  = N / 4;       // 2490368 float4 chunks
constexpr int BLOCKSZ = 256;
constexpr int GRID    = 1024;        // 4 blocks/CU; 9.5 chunks/thread
constexpr int CSTRIDE = GRID * BLOCKSZ;   // 262144

// Per-block partials in d_ws: part[block][slot], slot 0..7 = sum(err^2) for
// bin slot+1, slot 8..15 = count for bin slot+1. Plain stores — NO atomics,
// NO fences (R2: same-address atomics + threadfence cost ~100 us).
// R7: global_load_lds staging = 47.6 us (regression) — VGPR nt loads win.
constexpr int NSLOT = 16;

typedef float vfloat4 __attribute__((ext_vector_type(4)));
typedef int   vint4   __attribute__((ext_vector_type(4)));

__device__ __forceinline__ void load3(const float* __restrict__ pred,
                                      const float* __restrict__ gt,
                                      const int*   __restrict__ wm,
                                      int c, vfloat4& p, vfloat4& g, vint4& w)
{
    const int i0 = c * 4;            // flat element index
    const int b  = i0 / HW;          // batch (magic-mul by compiler)
    // nt loads: L1 bypass moved the read plateau 2.44 -> ~3.3 TB/s (R5/R6).
    p = __builtin_nontemporal_load((const vfloat4*)(pred + (i0 + b * HW)));
    g = __builtin_nontemporal_load((const vfloat4*)(gt + i0));
    w = __builtin_nontemporal_load((const vint4*)(wm + i0));
}

__device__ __forceinline__ void accum(const vfloat4& p, const vfloat4& g,
                                      const vint4& w, float* sum, int* cnt)
{
    const float e0 = p.x - g.x, e1 = p.y - g.y;
    const float e2 = p.z - g.z, e3 = p.w - g.w;
    const float s0 = e0 * e0, s1 = e1 * e1, s2 = e2 * e2, s3 = e3 * e3;
#pragma unroll
    for (int j = 0; j < 8; ++j) {
        const int bin = j + 1;
        sum[j] += (w.x == bin) ? s0 : 0.f;
        cnt[j] += (w.x == bin) ? 1 : 0;
        sum[j] += (w.y == bin) ? s1 : 0.f;
        cnt[j] += (w.y == bin) ? 1 : 0;
        sum[j] += (w.z == bin) ? s2 : 0.f;
        cnt[j] += (w.z == bin) ? 1 : 0;
        sum[j] += (w.w == bin) ? s3 : 0.f;
        cnt[j] += (w.w == bin) ? 1 : 0;
    }
}

// __launch_bounds__(256, 4): VGPR cap 128 so the allocator keeps the
// depth-4 pipeline's 48 data VGPRs live (R1-R4 compiled to VGPR=32 and
// silently serialized all loads).
__global__ __launch_bounds__(BLOCKSZ, 4) void seg_mse_kernel(
    const float* __restrict__ pred,
    const float* __restrict__ gt,
    const int*   __restrict__ wm,
    float* __restrict__ part)
{
    float sum[8] = {0.f, 0.f, 0.f, 0.f, 0.f, 0.f, 0.f, 0.f};
    int   cnt[8] = {0, 0, 0, 0, 0, 0, 0, 0};

    const int start = blockIdx.x * BLOCKSZ + threadIdx.x;

    // Depth-4 rotated pipeline: 4 chunk buffers (12 loads = 48 data VGPRs)
    // perpetually outstanding. Every thread has >= 9 chunks (NCHUNK/CSTRIDE
    // = 9.5), so the 4-deep prologue is always in-bounds.
    vfloat4 p0, g0, p1, g1, p2, g2, p3, g3;
    vint4   w0, w1, w2, w3;
    load3(pred, gt, wm, start,               p0, g0, w0);
    load3(pred, gt, wm, start + CSTRIDE,     p1, g1, w1);
    load3(pred, gt, wm, start + 2 * CSTRIDE, p2, g2, w2);
    load3(pred, gt, wm, start + 3 * CSTRIDE, p3, g3, w3);
    int next = start + 4 * CSTRIDE;

    while (true) {
        accum(p0, g0, w0, sum, cnt);
        if (next < NCHUNK) { load3(pred, gt, wm, next, p0, g0, w0); next += CSTRIDE; }
        else { accum(p1, g1, w1, sum, cnt); accum(p2, g2, w2, sum, cnt);
               accum(p3, g3, w3, sum, cnt); break; }

        accum(p1, g1, w1, sum, cnt);
        if (next < NCHUNK) { load3(pred, gt, wm, next, p1, g1, w1); next += CSTRIDE; }
        else { accum(p2, g2, w2, sum, cnt); accum(p3, g3, w3, sum, cnt);
               accum(p0, g0, w0, sum, cnt); break; }

        accum(p2, g2, w2, sum, cnt);
        if (next < NCHUNK) { load3(pred, gt, wm, next, p2, g2, w2); next += CSTRIDE; }
        else { accum(p3, g3, w3, sum, cnt); accum(p0, g0, w0, sum, cnt);
               accum(p1, g1, w1, sum, cnt); break; }

        accum(p3, g3, w3, sum, cnt);
        if (next < NCHUNK) { load3(pred, gt, wm, next, p3, g3, w3); next += CSTRIDE; }
        else { accum(p0, g0, w0, sum, cnt); accum(p1, g1, w1, sum, cnt);
               accum(p2, g2, w2, sum, cnt); break; }
    }

    // wave (64-lane) butterfly reduction of all 16 partials
    float fcnt[8];
#pragma unroll
    for (int j = 0; j < 8; ++j) fcnt[j] = (float)cnt[j];
#pragma unroll
    for (int j = 0; j < 8; ++j) {
#pragma unroll
        for (int off = 32; off > 0; off >>= 1) {
            sum[j]  += __shfl_down(sum[j], off);
            fcnt[j] += __shfl_down(fcnt[j], off);
        }
    }

    // cross-wave reduction in LDS (256 threads = 4 waves)
    __shared__ float lsum[4][8];
    __shared__ float lcnt[4][8];
    const int wave = threadIdx.x >> 6;
    const int lane = threadIdx.x & 63;
    if (lane == 0) {
#pragma unroll
        for (int j = 0; j < 8; ++j) {
            lsum[wave][j] = sum[j];
            lcnt[wave][j] = fcnt[j];
        }
    }
    __syncthreads();

    // 16 plain coalesced stores per block (one 64B segment)
    if (threadIdx.x < 8) {
        const int j = threadIdx.x;
        part[blockIdx.x * NSLOT + j] =
            lsum[0][j] + lsum[1][j] + lsum[2][j] + lsum[3][j];
    } else if (threadIdx.x < 16) {
        const int j = threadIdx.x - 8;
        part[blockIdx.x * NSLOT + 8 + j] =
            lcnt[0][j] + lcnt[1][j] + lcnt[2][j] + lcnt[3][j];
    }
}

// Single-block reduction of GRID x 16 partials (64 KB, L2-resident).
__global__ __launch_bounds__(1024) void finalize_kernel(
    const float* __restrict__ part,
    float* __restrict__ out)
{
    const int tid = threadIdx.x;
    const int j   = tid & 15;        // slot
    const int g   = tid >> 4;        // group 0..63
    float v = 0.f;
#pragma unroll
    for (int i = 0; i < GRID / 64; ++i) {
        v += part[(g + 64 * i) * NSLOT + j];
    }
    // combine groups within the wave: lanes differing in bits 4,5 share slot j
    v += __shfl_xor(v, 16);
    v += __shfl_xor(v, 32);

    // cross-wave: 16 waves each contribute one value per slot
    __shared__ float wsum[16][16];
    const int wave = tid >> 6;
    const int lane = tid & 63;
    if (lane < 16) wsum[wave][lane] = v;
    __syncthreads();

    __shared__ float fin[16];
    if (tid < 16) {
        float t = 0.f;
#pragma unroll
        for (int w = 0; w < 16; ++w) t += wsum[w][tid];
        fin[tid] = t;
    }
    __syncthreads();

    if (tid == 0) {
        float total = 0.f;
#pragma unroll
        for (int j2 = 0; j2 < 8; ++j2) {
            total += fin[j2] / fmaxf(fin[8 + j2], 1.f);
        }
        out[0] = total * (1.f / 8.f);
    }
}

extern "C" void kernel_launch(void* const* d_in, const int* in_sizes, int n_in,
                              void* d_out, int out_size, void* d_ws, size_t ws_size,
                              hipStream_t stream)
{
    const float* pred = (const float*)d_in[0];  // [32,2,256,1216] f32
    const float* gt   = (const float*)d_in[1];  // [32,1,256,1216] f32
    const int*   wm   = (const int*)d_in[2];    // [32,1,256,1216] i32
    float* part = (float*)d_ws;                 // GRID*16 floats = 64 KB

    // No memset needed: every part[] slot is written by the main kernel.
    seg_mse_kernel<<<GRID, BLOCKSZ, 0, stream>>>(pred, gt, wm, part);
    finalize_kernel<<<1, 1024, 0, stream>>>(part, (float*)d_out);
}

// Round 9
// 160.524 us; speedup vs baseline: 1.1152x; 1.1152x over previous
//
#include <hip/hip_runtime.h>

// Problem constants (from reference setup_inputs)
constexpr int B  = 32;
constexpr int H  = 256;
constexpr int W  = 1216;
constexpr int HW = H * W;            // 311296 (divisible by 4)
constexpr int N  = B * HW;           // 9961472 elements in gt / weight_map
constexpr int NCHUNK  = N / 4;       // 2490368 float4 chunks
constexpr int BLOCKSZ = 256;
constexpr int GRID    = 1024;        // 4 blocks/CU; 9.5 chunks/thread (steady state)
constexpr int CSTRIDE = GRID * BLOCKSZ;   // 262144

// Per-block partials in d_ws: part[block][slot], slot 0..7 = sum(err^2) for
// bin slot+1, slot 8..15 = count for bin slot+1. Plain stores — NO atomics,
// NO fences (R2: same-address atomics + threadfence cost ~100 us).
// History: R7 global_load_lds staging = 47.6 us (regression); R8 depth-4
// pipeline = +20 us vs depth-3 (tail bloat / pressure). Depth-3 is optimal.
constexpr int NSLOT = 16;

typedef float vfloat4 __attribute__((ext_vector_type(4)));
typedef int   vint4   __attribute__((ext_vector_type(4)));

__device__ __forceinline__ void load3(const float* __restrict__ pred,
                                      const float* __restrict__ gt,
                                      const int*   __restrict__ wm,
                                      int c, vfloat4& p, vfloat4& g, vint4& w)
{
    const int i0 = c * 4;            // flat element index
    const int b  = i0 / HW;          // batch (magic-mul by compiler)
    // nt loads: L1 bypass moved the read plateau 2.44 -> ~3.3-3.5 TB/s (R5/R6).
    p = __builtin_nontemporal_load((const vfloat4*)(pred + (i0 + b * HW)));
    g = __builtin_nontemporal_load((const vfloat4*)(gt + i0));
    w = __builtin_nontemporal_load((const vint4*)(wm + i0));
}

__device__ __forceinline__ void accum(const vfloat4& p, const vfloat4& g,
                                      const vint4& w, float* sum, int* cnt)
{
    const float e0 = p.x - g.x, e1 = p.y - g.y;
    const float e2 = p.z - g.z, e3 = p.w - g.w;
    const float s0 = e0 * e0, s1 = e1 * e1, s2 = e2 * e2, s3 = e3 * e3;
#pragma unroll
    for (int j = 0; j < 8; ++j) {
        const int bin = j + 1;
        sum[j] += (w.x == bin) ? s0 : 0.f;
        cnt[j] += (w.x == bin) ? 1 : 0;
        sum[j] += (w.y == bin) ? s1 : 0.f;
        cnt[j] += (w.y == bin) ? 1 : 0;
        sum[j] += (w.z == bin) ? s2 : 0.f;
        cnt[j] += (w.z == bin) ? 1 : 0;
        sum[j] += (w.w == bin) ? s3 : 0.f;
        cnt[j] += (w.w == bin) ? 1 : 0;
    }
}

// __launch_bounds__(256, 4): VGPR cap 128 so the allocator keeps the
// depth-3 pipeline's 36 data VGPRs live (R1-R4 compiled to VGPR=32 and
// silently serialized all loads).
__global__ __launch_bounds__(BLOCKSZ, 4) void seg_mse_kernel(
    const float* __restrict__ pred,
    const float* __restrict__ gt,
    const int*   __restrict__ wm,
    float* __restrict__ part)
{
    float sum[8] = {0.f, 0.f, 0.f, 0.f, 0.f, 0.f, 0.f, 0.f};
    int   cnt[8] = {0, 0, 0, 0, 0, 0, 0, 0};

    const int start = blockIdx.x * BLOCKSZ + threadIdx.x;

    // Depth-3 rotated pipeline: 3 chunk buffers (9 loads = 36 data VGPRs)
    // perpetually outstanding. Every thread has >= 9 chunks (NCHUNK/CSTRIDE
    // = 9.5), so the 3-deep prologue is always in-bounds.
    vfloat4 p0, g0, p1, g1, p2, g2;
    vint4   w0, w1, w2;
    load3(pred, gt, wm, start,               p0, g0, w0);
    load3(pred, gt, wm, start + CSTRIDE,     p1, g1, w1);
    load3(pred, gt, wm, start + 2 * CSTRIDE, p2, g2, w2);
    int next = start + 3 * CSTRIDE;

    while (true) {
        accum(p0, g0, w0, sum, cnt);
        if (next < NCHUNK) { load3(pred, gt, wm, next, p0, g0, w0); next += CSTRIDE; }
        else { accum(p1, g1, w1, sum, cnt); accum(p2, g2, w2, sum, cnt); break; }

        accum(p1, g1, w1, sum, cnt);
        if (next < NCHUNK) { load3(pred, gt, wm, next, p1, g1, w1); next += CSTRIDE; }
        else { accum(p2, g2, w2, sum, cnt); accum(p0, g0, w0, sum, cnt); break; }

        accum(p2, g2, w2, sum, cnt);
        if (next < NCHUNK) { load3(pred, gt, wm, next, p2, g2, w2); next += CSTRIDE; }
        else { accum(p0, g0, w0, sum, cnt); accum(p1, g1, w1, sum, cnt); break; }
    }

    // wave (64-lane) butterfly reduction of all 16 partials
    float fcnt[8];
#pragma unroll
    for (int j = 0; j < 8; ++j) fcnt[j] = (float)cnt[j];
#pragma unroll
    for (int j = 0; j < 8; ++j) {
#pragma unroll
        for (int off = 32; off > 0; off >>= 1) {
            sum[j]  += __shfl_down(sum[j], off);
            fcnt[j] += __shfl_down(fcnt[j], off);
        }
    }

    // cross-wave reduction in LDS (256 threads = 4 waves)
    __shared__ float lsum[4][8];
    __shared__ float lcnt[4][8];
    const int wave = threadIdx.x >> 6;
    const int lane = threadIdx.x & 63;
    if (lane == 0) {
#pragma unroll
        for (int j = 0; j < 8; ++j) {
            lsum[wave][j] = sum[j];
            lcnt[wave][j] = fcnt[j];
        }
    }
    __syncthreads();

    // 16 plain coalesced stores per block (one 64B segment)
    if (threadIdx.x < 8) {
        const int j = threadIdx.x;
        part[blockIdx.x * NSLOT + j] =
            lsum[0][j] + lsum[1][j] + lsum[2][j] + lsum[3][j];
    } else if (threadIdx.x < 16) {
        const int j = threadIdx.x - 8;
        part[blockIdx.x * NSLOT + 8 + j] =
            lcnt[0][j] + lcnt[1][j] + lcnt[2][j] + lcnt[3][j];
    }
}

// Single-block reduction of GRID x 16 partials (64 KB, L2-resident).
__global__ __launch_bounds__(1024) void finalize_kernel(
    const float* __restrict__ part,
    float* __restrict__ out)
{
    const int tid = threadIdx.x;
    const int j   = tid & 15;        // slot
    const int g   = tid >> 4;        // group 0..63
    float v = 0.f;
#pragma unroll
    for (int i = 0; i < GRID / 64; ++i) {
        v += part[(g + 64 * i) * NSLOT + j];
    }
    // combine groups within the wave: lanes differing in bits 4,5 share slot j
    v += __shfl_xor(v, 16);
    v += __shfl_xor(v, 32);

    // cross-wave: 16 waves each contribute one value per slot
    __shared__ float wsum[16][16];
    const int wave = tid >> 6;
    const int lane = tid & 63;
    if (lane < 16) wsum[wave][lane] = v;
    __syncthreads();

    __shared__ float fin[16];
    if (tid < 16) {
        float t = 0.f;
#pragma unroll
        for (int w = 0; w < 16; ++w) t += wsum[w][tid];
        fin[tid] = t;
    }
    __syncthreads();

    if (tid == 0) {
        float total = 0.f;
#pragma unroll
        for (int j2 = 0; j2 < 8; ++j2) {
            total += fin[j2] / fmaxf(fin[8 + j2], 1.f);
        }
        out[0] = total * (1.f / 8.f);
    }
}

extern "C" void kernel_launch(void* const* d_in, const int* in_sizes, int n_in,
                              void* d_out, int out_size, void* d_ws, size_t ws_size,
                              hipStream_t stream)
{
    const float* pred = (const float*)d_in[0];  // [32,2,256,1216] f32
    const float* gt   = (const float*)d_in[1];  // [32,1,256,1216] f32
    const int*   wm   = (const int*)d_in[2];    // [32,1,256,1216] i32
    float* part = (float*)d_ws;                 // GRID*16 floats = 64 KB

    // No memset needed: every part[] slot is written by the main kernel.
    seg_mse_kernel<<<GRID, BLOCKSZ, 0, stream>>>(pred, gt, wm, part);
    finalize_kernel<<<1, 1024, 0, stream>>>(part, (float*)d_out);
}